// Round 4
// baseline (70.658 us; speedup 1.0000x reference)
//
#include <hip/hip_runtime.h>
#include <math.h>
#include <limits.h>

#define HH 128
#define WW 128
#define HW (HH*WW)
#define BB 2
#define CC 14
#define NPAIR 26   // B * (C-1)
#define RPB 16                     // rows per k_C block (2 rows per thread)
#define NBLK (NPAIR * (HH / RPB))  // 208 blocks -> ONE block-round on 256 CUs

typedef unsigned long long u64;

// ---------------------------------------------------------------------------
// ws layout (bytes):
//   Scol : [BB][CC][WW][16] u8 @ 0       (57344)  column bitmask bytes of the
//          student class-c argmax mask: byte g = rows 8g..8g+7 (bit r = row 8g+r)
//   Tcol : same for teacher      @ 57344  (57344)
//   Hcol : same for (Ls[c]>0.5)  @ 114688 (57344)
//   partials : [NBLK] f32        @ 172032 (832)   per-block loss partial sums
//
// Round-3 post-mortem: fence/ticket removal paid (-3.5us). This round:
// single block-round (208 blocks), per-thread register mask build (no
// preamble barrier, no mask LDS), 2 rows/thread so mask setup is paid once.
// ---------------------------------------------------------------------------

// distance from row i to nearest set bit in 128-bit mask {lo,hi}; 255 if empty.
// i is wave-uniform in k_C -> uniform branches.
__device__ inline int nbd(u64 lo, u64 hi, int i) {
    int up = 255, down = 255;
    u64 slo, shi;
    if (i == 0)      { slo = lo; shi = hi; }
    else if (i < 64) { slo = (lo >> i) | (hi << (64 - i)); shi = hi >> i; }
    else             { slo = hi >> (i - 64); shi = 0ULL; }
    if (slo)      up = __builtin_ctzll(slo);
    else if (shi) up = 64 + __builtin_ctzll(shi);
    int s = 127 - i;
    u64 llo, lhi;
    if (s == 0)      { llo = lo; lhi = hi; }
    else if (s < 64) { lhi = (hi << s) | (lo >> (64 - s)); llo = lo << s; }
    else             { lhi = lo << (s - 64); llo = 0ULL; }
    if (lhi)      down = __builtin_clzll(lhi);
    else if (llo) down = 64 + __builtin_clzll(llo);
    return min(up, down);
}

__device__ inline ulonglong2 ld16z(const unsigned char* p, size_t off, bool ok) {
    return ok ? *(const ulonglong2*)(p + off) : make_ulonglong2(0ULL, 0ULL);
}

// fused argmax (student+teacher) + direct emission of per-class packed column
// bitmask bytes. Each block owns 8 rows of one batch image; after the argmax,
// an LDS transpose lets 256 threads byte-pack all 13 classes' S/T/H masks.
__global__ void k_pack(const float* __restrict__ Ls, const float* __restrict__ Lt,
                       unsigned char* __restrict__ Scol, unsigned char* __restrict__ Tcol,
                       unsigned char* __restrict__ Hcol) {
    int tid = threadIdx.x;
    int p4 = blockIdx.x * 256 + tid;          // 0..8191 (4 px each)
    int b = p4 >> 12;                         // uniform per block
    int q4 = p4 & (HW / 4 - 1);
    const float4* bs = (const float4*)(Ls + (size_t)b * CC * HW) + q4;
    const float4* bt = (const float4*)(Lt + (size_t)b * CC * HW) + q4;
    float4 mS = bs[0], mT = bt[0];
    uchar4 iS = make_uchar4(0, 0, 0, 0), iT = make_uchar4(0, 0, 0, 0);
    ushort4 hm = make_ushort4(0, 0, 0, 0);
#pragma unroll
    for (int c = 1; c < CC; ++c) {
        float4 v = bs[(size_t)c * (HW / 4)];
        if (v.x > mS.x) { mS.x = v.x; iS.x = (unsigned char)c; }   // first-max tie rule
        if (v.y > mS.y) { mS.y = v.y; iS.y = (unsigned char)c; }
        if (v.z > mS.z) { mS.z = v.z; iS.z = (unsigned char)c; }
        if (v.w > mS.w) { mS.w = v.w; iS.w = (unsigned char)c; }
        unsigned short bit = (unsigned short)(1u << (c - 1));
        if (v.x > 0.5f) hm.x |= bit;
        if (v.y > 0.5f) hm.y |= bit;
        if (v.z > 0.5f) hm.z |= bit;
        if (v.w > 0.5f) hm.w |= bit;
        float4 u = bt[(size_t)c * (HW / 4)];
        if (u.x > mT.x) { mT.x = u.x; iT.x = (unsigned char)c; }
        if (u.y > mT.y) { mT.y = u.y; iT.y = (unsigned char)c; }
        if (u.z > mT.z) { mT.z = u.z; iT.z = (unsigned char)c; }
        if (u.w > mT.w) { mT.w = u.w; iT.w = (unsigned char)c; }
    }
    // LDS transpose: block covers rows [8g, 8g+8) of image b, g = blk & 15
    __shared__ unsigned char  labL[8][WW];
    __shared__ unsigned short hL[8][WW];
    int r  = tid >> 5;                 // local row 0..7
    int c4 = (tid & 31) * 4;           // starting column
    *(uchar4*)&labL[r][c4] = make_uchar4(
        (unsigned char)(iS.x | (iT.x << 4)), (unsigned char)(iS.y | (iT.y << 4)),
        (unsigned char)(iS.z | (iT.z << 4)), (unsigned char)(iS.w | (iT.w << 4)));
    *(ushort4*)&hL[r][c4] = hm;
    __syncthreads();

    int j  = tid & (WW - 1);
    int g  = blockIdx.x & 15;          // 8-row group index within image
    int n0 = b * CC;
    if (tid < 128) {                   // threads 0..127: student + teacher masks
        unsigned char lr[8];
#pragma unroll
        for (int rr = 0; rr < 8; ++rr) lr[rr] = labL[rr][j];
#pragma unroll
        for (int cc = 1; cc < CC; ++cc) {
            unsigned int sb = 0, tb = 0;
#pragma unroll
            for (int rr = 0; rr < 8; ++rr) {
                sb |= (unsigned int)((lr[rr] & 15) == cc) << rr;
                tb |= (unsigned int)((lr[rr] >> 4)  == cc) << rr;
            }
            size_t off = ((size_t)(((n0 + cc) << 7) | j) << 4) + g;
            Scol[off] = (unsigned char)sb;
            Tcol[off] = (unsigned char)tb;
        }
    } else {                           // threads 128..255: hbit masks
        unsigned short hr[8];
#pragma unroll
        for (int rr = 0; rr < 8; ++rr) hr[rr] = hL[rr][j];
#pragma unroll
        for (int cc = 1; cc < CC; ++cc) {
            unsigned int hbb = 0;
#pragma unroll
            for (int rr = 0; rr < 8; ++rr) hbb |= ((hr[rr] >> (cc - 1)) & 1u) << rr;
            size_t off = ((size_t)(((n0 + cc) << 7) | j) << 4) + g;
            Hcol[off] = (unsigned char)hbb;
        }
    }
}

// One block per (pair, 16-row group), 1024 threads, 2 output rows per thread.
// Every thread builds its own column's masks in REGISTERS (7x16B L2 loads +
// ~60 bit-ops, redundant across the 8 k-groups) -> no preamble barrier, no
// mask LDS. Single barrier publishes sq + flags; ring; reduce; plain store.
__global__ __launch_bounds__(1024) void k_C(
        const unsigned char* __restrict__ Scol, const unsigned char* __restrict__ Tcol,
        const unsigned char* __restrict__ Hcol, const float* __restrict__ Ls,
        float* __restrict__ partials) {
    int n = blockIdx.x >> 3;          // pair (8 groups per pair)
    int g = blockIdx.x & 7;           // 16-row group
    int tid = threadIdx.x;
    int k = tid >> 7;                 // 0..7 (wave-uniform)
    int j = tid & (WW - 1);
    int b = n / (CC - 1), c = 1 + (n - b * (CC - 1));
    const float* Lp = Ls + (size_t)(b * CC + c) * HW;

    int i0 = g * RPB + k;             // this thread's two output rows
    int i1 = i0 + 8;
    float lv0 = Lp[i0 * WW + j];      // coalesced, issued early
    float lv1 = Lp[i1 * WW + j];

    // per-thread register mask build for column j
    size_t cbase = ((size_t)(((b * CC + c) << 7) | j)) << 4;
    ulonglong2 S  = *(const ulonglong2*)(Scol + cbase);
    ulonglong2 Sl = ld16z(Scol, cbase - 16, j > 0);
    ulonglong2 Sr = ld16z(Scol, cbase + 16, j < WW - 1);
    ulonglong2 T  = *(const ulonglong2*)(Tcol + cbase);
    ulonglong2 Tl = ld16z(Tcol, cbase - 16, j > 0);
    ulonglong2 Tr = ld16z(Tcol, cbase + 16, j < WW - 1);
    ulonglong2 Hc = *(const ulonglong2*)(Hcol + cbase);

    // erosion: m & up & down & left & right; shifts insert 0 (border erodes)
    u64 ms0 = S.x, ms1 = S.y;
    u64 U0 = ms0 << 1, U1 = (ms1 << 1) | (ms0 >> 63);
    u64 D0 = (ms0 >> 1) | (ms1 << 63), D1 = ms1 >> 1;
    u64 er0 = ms0 & U0 & D0 & Sl.x & Sr.x;
    u64 er1 = ms1 & U1 & D1 & Sl.y & Sr.y;
    u64 es0 = ms0 & ~er0, es1 = ms1 & ~er1;
    u64 fp0 = es0 & Hc.x, fp1 = es1 & Hc.y;       // pred = es*logit > 0.5

    u64 mt0 = T.x, mt1 = T.y;
    u64 Ut0 = mt0 << 1, Ut1 = (mt1 << 1) | (mt0 >> 63);
    u64 Dt0 = (mt0 >> 1) | (mt1 << 63), Dt1 = mt1 >> 1;
    u64 ert0 = mt0 & Ut0 & Dt0 & Tl.x & Tr.x;
    u64 ert1 = mt1 & Ut1 & Dt1 & Tl.y & Tr.y;
    u64 et0 = mt0 & ~ert0, et1 = mt1 & ~ert1;

    __shared__ int sfl[2];
    __shared__ uchar4 sq[RPB][WW];    // d1 per map (255 sentinel; squared on read)

    // flags: waves 0-1 (k==0) span all 128 columns; published under the sq barrier
    if (tid < 128) {
        u64 bFgP = __ballot((fp0 | fp1) != 0ull);
        u64 bBgP = __ballot((fp0 & fp1) != ~0ull);
        u64 bFgT = __ballot((et0 | et1) != 0ull);
        u64 bBgT = __ballot((et0 & et1) != ~0ull);
        if ((tid & 63) == 0)
            sfl[tid >> 6] = (bFgP ? 1 : 0) | (bBgP ? 2 : 0)
                          | (bFgT ? 4 : 0) | (bBgT ? 8 : 0);
    }

    // column EDT from registers, both rows
    int dP0  = nbd(fp0, fp1, i0),  dPb0 = nbd(~fp0, ~fp1, i0);
    int dT0  = nbd(et0, et1, i0),  dTb0 = nbd(~et0, ~et1, i0);
    int dP1  = nbd(fp0, fp1, i1),  dPb1 = nbd(~fp0, ~fp1, i1);
    int dT1  = nbd(et0, et1, i1),  dTb1 = nbd(~et0, ~et1, i1);

    sq[k][j]     = make_uchar4((unsigned char)dP0, (unsigned char)dPb0,
                               (unsigned char)dT0, (unsigned char)dTb0);
    sq[k + 8][j] = make_uchar4((unsigned char)dP1, (unsigned char)dPb1,
                               (unsigned char)dT1, (unsigned char)dTb1);
    __syncthreads();                  // ONE barrier publishes sq + sfl

    int f = sfl[0] | sfl[1];
    bool aP = (f & 3) == 3, aT = (f & 12) == 12;

    int bP0 = dP0 * dP0, bPb0 = dPb0 * dPb0, bT0 = dT0 * dT0, bTb0 = dTb0 * dTb0;
    int bP1 = dP1 * dP1, bPb1 = dPb1 * dPb1, bT1 = dT1 * dT1, bTb1 = dTb1 * dTb1;
    int need = 0;
    if (aP) need = max(max(bP0, bPb0), max(bP1, bPb1));
    if (aT) need = max(need, max(max(bT0, bTb0), max(bT1, bTb1)));
    // expanding ring: candidates at radius rad are >= rad^2, so once
    // rad^2 >= need (best over maps actually used), the min is final.
    for (int rad = 1; rad < WW; ++rad) {
        int rr = rad * rad;
        if (rr >= need) break;
        if (j >= rad) {
            uchar4 sA = sq[k][j - rad];
            uchar4 sB = sq[k + 8][j - rad];
            bP0 = min(bP0, (int)sA.x * sA.x + rr); bPb0 = min(bPb0, (int)sA.y * sA.y + rr);
            bT0 = min(bT0, (int)sA.z * sA.z + rr); bTb0 = min(bTb0, (int)sA.w * sA.w + rr);
            bP1 = min(bP1, (int)sB.x * sB.x + rr); bPb1 = min(bPb1, (int)sB.y * sB.y + rr);
            bT1 = min(bT1, (int)sB.z * sB.z + rr); bTb1 = min(bTb1, (int)sB.w * sB.w + rr);
        }
        if (j + rad < WW) {
            uchar4 sA = sq[k][j + rad];
            uchar4 sB = sq[k + 8][j + rad];
            bP0 = min(bP0, (int)sA.x * sA.x + rr); bPb0 = min(bPb0, (int)sA.y * sA.y + rr);
            bT0 = min(bT0, (int)sA.z * sA.z + rr); bTb0 = min(bTb0, (int)sA.w * sA.w + rr);
            bP1 = min(bP1, (int)sB.x * sB.x + rr); bPb1 = min(bPb1, (int)sB.y * sB.y + rr);
            bT1 = min(bT1, (int)sB.z * sB.z + rr); bTb1 = min(bTb1, (int)sB.w * sB.w + rr);
        }
        need = 0;
        if (aP) need = max(max(bP0, bPb0), max(bP1, bPb1));
        if (aT) need = max(need, max(max(bT0, bTb0), max(bT1, bTb1)));
    }

    float fieldP0 = aP ? (float)(bP0 + bPb0) : 0.0f;
    float fieldT0 = aT ? (float)(bT0 + bTb0) : 0.0f;
    float fieldP1 = aP ? (float)(bP1 + bPb1) : 0.0f;
    float fieldT1 = aT ? (float)(bT1 + bTb1) : 0.0f;

    bool es_0 = ((i0 < 64 ? (es0 >> i0) : (es1 >> (i0 - 64))) & 1ull) != 0;
    bool et_0 = ((i0 < 64 ? (et0 >> i0) : (et1 >> (i0 - 64))) & 1ull) != 0;
    bool es_1 = ((i1 < 64 ? (es0 >> i1) : (es1 >> (i1 - 64))) & 1ull) != 0;
    bool et_1 = ((i1 < 64 ? (et0 >> i1) : (et1 >> (i1 - 64))) & 1ull) != 0;
    float pv0 = es_0 ? lv0 : 0.0f, tv0 = et_0 ? (float)c : 0.0f;
    float pv1 = es_1 ? lv1 : 0.0f, tv1 = et_1 ? (float)c : 0.0f;
    float d0 = pv0 - tv0, d1 = pv1 - tv1;
    float v = d0 * d0 * (fieldP0 + fieldT0) + d1 * d1 * (fieldP1 + fieldT1);

    for (int o = 32; o > 0; o >>= 1) v += __shfl_down(v, o);
    __shared__ float wsum[16];
    int lane = tid & 63, w = tid >> 6;
    if (lane == 0) wsum[w] = v;
    __syncthreads();
    if (tid == 0) {
        float tot = 0.0f;
#pragma unroll
        for (int q = 0; q < 16; ++q) tot += wsum[q];
        partials[blockIdx.x] = tot;   // private slot: no atomic, no fence
    }
}

// final reduction: 208 partials -> 26 pair losses -> scalar. One 64-thread
// block; kernel boundary guarantees k_C's stores are visible.
__global__ void k_fin(const float* __restrict__ partials, float* __restrict__ out) {
    int tid = threadIdx.x;            // 0..63
    float vv = 0.0f;
    if (tid < NPAIR) {
        float s = 0.0f;
#pragma unroll
        for (int t = 0; t < 8; ++t) s += partials[tid * 8 + t];
        vv = logf(s * (1.0f / (float)HW) + 1.0f);
    }
    for (int o = 32; o > 0; o >>= 1) vv += __shfl_down(vv, o);
    if (tid == 0) out[0] = 0.5f * vv; // (1 - LOSS_WEIGHT) * sum
}

extern "C" void kernel_launch(void* const* d_in, const int* in_sizes, int n_in,
                              void* d_out, int out_size, void* d_ws, size_t ws_size,
                              hipStream_t stream) {
    const float* Ls = (const float*)d_in[0];
    const float* Lt = (const float*)d_in[1];
    float* out = (float*)d_out;

    char* w = (char*)d_ws;
    unsigned char* Sc   = (unsigned char*)(w);
    unsigned char* Tc   = (unsigned char*)(w + 57344);
    unsigned char* Hc   = (unsigned char*)(w + 114688);
    float*         part = (float*)        (w + 172032);

    k_pack<<<BB * HW / 4 / 256, 256, 0, stream>>>(Ls, Lt, Sc, Tc, Hc);
    k_C<<<NBLK, 1024, 0, stream>>>(Sc, Tc, Hc, Ls, part);
    k_fin<<<1, 64, 0, stream>>>(part, out);
}